// Round 19
// baseline (166.104 us; speedup 1.0000x reference)
//
#include <hip/hip_runtime.h>

typedef unsigned short u16;
typedef unsigned int u32;
typedef __attribute__((ext_vector_type(8))) __bf16 bf16x8;
typedef __attribute__((ext_vector_type(2))) __bf16 bf16x2;
typedef __attribute__((ext_vector_type(4))) float f32x4;
typedef __attribute__((ext_vector_type(16))) float f32x16;
typedef __attribute__((ext_vector_type(4))) u32 u32x4;

__device__ inline u16 f2bf(float f) {
  unsigned u = __builtin_bit_cast(unsigned, f);
  u += 0x7FFFu + ((u >> 16) & 1u);
  return (u16)(u >> 16);
}

__device__ inline u32 packbf(float a, float b) {
  bf16x2 t;
  t[0] = (__bf16)a;
  t[1] = (__bf16)b;
  return __builtin_bit_cast(u32, t);
}

__device__ inline void async16(const void* g, void* l) {
  __builtin_amdgcn_global_load_lds((const __attribute__((address_space(1))) void*)g,
                                   (__attribute__((address_space(3))) void*)l, 16, 0, 0);
}

// ---------------- fused prep: x fp32->bf16 (z==4) + 4x weight transpose (z<4) ----------------
// z==0 (W_Q) folds 0.125*log2(e) so QK^T comes out in exp2 domain.
__global__ __launch_bounds__(256) void prep(const float* __restrict__ x, u16* __restrict__ xb,
                                            const float* __restrict__ W0,
                                            const float* __restrict__ W1,
                                            const float* __restrict__ W2,
                                            const float* __restrict__ W3,
                                            u16* __restrict__ WtQKV,
                                            u16* __restrict__ WtO) {
  const int z = blockIdx.z;
  if (z == 4) {
    const int base = (blockIdx.y * 32 + blockIdx.x) * 4 * 256 + threadIdx.x;
#pragma unroll
    for (int it = 0; it < 4; ++it) {
      const int i = base + it * 256;
      float4 v = ((const float4*)x)[i];
      ushort4 r;
      r.x = f2bf(v.x); r.y = f2bf(v.y); r.z = f2bf(v.z); r.w = f2bf(v.w);
      ((ushort4*)xb)[i] = r;
    }
    return;
  }
  __shared__ u16 tile[32][33];
  const float* W = (z == 0) ? W0 : (z == 1) ? W1 : (z == 2) ? W2 : W3;
  u16* Wt = (z < 3) ? (WtQKV + (size_t)z * 1024 * 1024) : WtO;
  const float s = (z == 0) ? 0.18033688011112042f : 1.0f;
  const int e0 = blockIdx.x * 32;
  const int d0 = blockIdx.y * 32;
  const int tx = threadIdx.x & 31;
  const int ty = threadIdx.x >> 5;
#pragma unroll
  for (int i = ty; i < 32; i += 8)
    tile[i][tx] = f2bf(W[(size_t)(d0 + i) * 1024 + e0 + tx] * s);
  __syncthreads();
#pragma unroll
  for (int i = ty; i < 32; i += 8)
    Wt[(size_t)(e0 + i) * 1024 + d0 + tx] = tile[tx][i];
}

// ---------------- QKV GEMM (R17 proven): C = A*Bt^T + fused sigma-permuted V^T ----------------
__global__ __launch_bounds__(256) void gemm_qkv(const u16* __restrict__ A,
                                                const u16* __restrict__ Bt,
                                                u16* __restrict__ C,
                                                u16* __restrict__ Vtg) {
  constexpr int K = 1024, N = 3072;
  __shared__ __align__(16) u16 As[128 * 32];
  __shared__ __align__(16) u16 Bs[128 * 32];
  const int tid = threadIdx.x;
  const int lane = tid & 63;
  const int wave = tid >> 6;
  const int lr = lane & 15;
  const int lk = (lane >> 4) * 8;
  const int wm = (wave >> 1) * 64;
  const int wn = (wave & 1) * 64;

  // chunked XCD swizzle (768 blocks, 768 % 8 == 0)
  const int flat = blockIdx.y * gridDim.x + blockIdx.x;
  const int chunk = (gridDim.x * gridDim.y) >> 3;
  const int nf = (flat & 7) * chunk + (flat >> 3);
  const int bm = (nf % gridDim.x) * 128;
  const int bn = (nf / gridDim.x) * 128;

  const int srow = lane >> 2;
  const int scol = (lane & 3) * 8;

  f32x4 acc[4][4] = {};

  for (int k0 = 0; k0 < K; k0 += 32) {
#pragma unroll
    for (int r = 0; r < 2; ++r) {
      const int chnk = r * 4 + wave;
      const int row = chnk * 16 + srow;
      async16(A + (size_t)(bm + row) * K + k0 + scol, &As[chnk * 512 + lane * 8]);
      async16(Bt + (size_t)(bn + row) * K + k0 + scol, &Bs[chnk * 512 + lane * 8]);
    }
    __syncthreads();
    bf16x8 a[4], b[4];
#pragma unroll
    for (int i = 0; i < 4; ++i) {
      a[i] = *(const bf16x8*)&As[(wm + i * 16 + lr) * 32 + lk];
      b[i] = *(const bf16x8*)&Bs[(wn + i * 16 + lr) * 32 + lk];
    }
#pragma unroll
    for (int mi = 0; mi < 4; ++mi)
#pragma unroll
      for (int ni = 0; ni < 4; ++ni)
        acc[mi][ni] = __builtin_amdgcn_mfma_f32_16x16x32_bf16(a[mi], b[ni], acc[mi][ni], 0, 0, 0);
    __syncthreads();
  }

#pragma unroll
  for (int mi = 0; mi < 4; ++mi) {
    const int row = bm + wm + mi * 16 + (lane >> 4) * 4;   // j spans row..row+3
#pragma unroll
    for (int ni = 0; ni < 4; ++ni) {
      const int col = bn + wn + ni * 16 + lr;
#pragma unroll
      for (int j = 0; j < 4; ++j)
        C[(size_t)(row + j) * N + col] = f2bf(acc[mi][ni][j]);
      if (col >= 2048) {
        const int bloc = row >> 11;
        const int s = row & 2047;
        const int sp = (s & ~12) | ((s & 4) << 1) | ((s & 8) >> 1);  // sigma: swap bits 2,3
        ushort4 v4;
        v4.x = f2bf(acc[mi][ni][0]);
        v4.y = f2bf(acc[mi][ni][1]);
        v4.z = f2bf(acc[mi][ni][2]);
        v4.w = f2bf(acc[mi][ni][3]);
        *(ushort4*)(Vtg + (size_t)(bloc * 1024 + (col - 2048)) * 2048 + sp) = v4;
      }
    }
  }
}

// ---------------- out-proj GEMM with FUSED combine in A-staging ----------------
// A(row, k) = (Opart0[row][k] + Opart1[row][k]) / (l0(row,h) + l1(row,h)), h = k>>6.
// Reg-staged A (2 global bf16x8 loads + 2 Lpart scalars + blend + ds_write); B via async16.
// Bit-identical to the old combine->Obuf->load path. out fp32.
__global__ __launch_bounds__(256) void gemm_out(const u16* __restrict__ Opart,
                                                const float* __restrict__ Lpart,
                                                const u16* __restrict__ Bt,
                                                float* __restrict__ out) {
  constexpr int K = 1024, N = 1024;
  __shared__ __align__(16) u16 As[128 * 32];
  __shared__ __align__(16) u16 Bs[128 * 32];
  const int tid = threadIdx.x;
  const int lane = tid & 63;
  const int wave = tid >> 6;
  const int lr = lane & 15;
  const int lk = (lane >> 4) * 8;
  const int wm = (wave >> 1) * 64;
  const int wn = (wave & 1) * 64;

  // chunked XCD swizzle (256 blocks, 256 % 8 == 0)
  const int flat = blockIdx.y * gridDim.x + blockIdx.x;
  const int chunk = (gridDim.x * gridDim.y) >> 3;
  const int nf = (flat & 7) * chunk + (flat >> 3);
  const int bm = (nf % gridDim.x) * 128;
  const int bn = (nf / gridDim.x) * 128;

  const int srow = lane >> 2;
  const int scol = (lane & 3) * 8;

  f32x4 acc[4][4] = {};

  for (int k0 = 0; k0 < K; k0 += 32) {
    const int hh = (k0 + scol) >> 6;
#pragma unroll
    for (int r = 0; r < 2; ++r) {
      const int chnk = r * 4 + wave;
      const int row = bm + chnk * 16 + srow;
      // fused combine: (O0 + O1) * 1/(l0 + l1)
      const bf16x8 a0 = *(const bf16x8*)(Opart + (size_t)row * 1024 + k0 + scol);
      const bf16x8 a1 = *(const bf16x8*)(Opart + (size_t)4096 * 1024 + (size_t)row * 1024 + k0 + scol);
      const float inv = 1.0f / (Lpart[(size_t)row * 16 + hh] +
                                Lpart[(size_t)4096 * 16 + (size_t)row * 16 + hh]);
      u16 tmp[8];
#pragma unroll
      for (int j = 0; j < 8; ++j) tmp[j] = f2bf(((float)a0[j] + (float)a1[j]) * inv);
      *(uint4*)&As[chnk * 512 + lane * 8] = *(uint4*)tmp;
      // B via direct-to-LDS
      async16(Bt + (size_t)(bn + chnk * 16 + srow) * K + k0 + scol, &Bs[chnk * 512 + lane * 8]);
    }
    __syncthreads();
    bf16x8 a[4], b[4];
#pragma unroll
    for (int i = 0; i < 4; ++i) {
      a[i] = *(const bf16x8*)&As[(wm + i * 16 + lr) * 32 + lk];
      b[i] = *(const bf16x8*)&Bs[(wn + i * 16 + lr) * 32 + lk];
    }
#pragma unroll
    for (int mi = 0; mi < 4; ++mi)
#pragma unroll
      for (int ni = 0; ni < 4; ++ni)
        acc[mi][ni] = __builtin_amdgcn_mfma_f32_16x16x32_bf16(a[mi], b[ni], acc[mi][ni], 0, 0, 0);
    __syncthreads();
  }

#pragma unroll
  for (int mi = 0; mi < 4; ++mi) {
    const int row = bm + wm + mi * 16 + (lane >> 4) * 4;
#pragma unroll
    for (int ni = 0; ni < 4; ++ni) {
      const int col = bn + wn + ni * 16 + lr;
#pragma unroll
      for (int j = 0; j < 4; ++j)
        out[(size_t)(row + j) * N + col] = acc[mi][ni][j];
    }
  }
}

// ---------------- Flash causal attention (R18 body: proven 56us) ----------------
__global__ __launch_bounds__(256, 2) void attn_kernel(const u16* __restrict__ QKV,
                                                      const u16* __restrict__ Vtg,
                                                      u16* __restrict__ Opart,
                                                      float* __restrict__ Lpart) {
  constexpr int S = 2048, LD = 3072;
  constexpr float MFIX = 12.0f;
  __shared__ __align__(16) u16 Ks[2][64 * 64];
  __shared__ __align__(16) u16 Vs[2][64 * 64];

  const int flat = blockIdx.y * 16 + blockIdx.x;
  const int nf = (flat & 7) * 64 + (flat >> 3);
  const int xi = nf & 15;
  const int bh = nf >> 4;

  const int g = 7 - (xi >> 1);
  const int c = xi & 1;
  const int b = bh >> 4, h = bh & 15;
  const int tid = threadIdx.x, lane = tid & 63, w = tid >> 6;
  const int l31 = lane & 31, lh = lane >> 5;

  const int qbase = g * 256 + w * 64;
  const int ktlast = 4 * g + w;
  const int ktbeg = c * (2 * g + 2);
  const int ktend = (c + 1) * (2 * g + 2);

  bf16x8 qf[2][4];
#pragma unroll
  for (int qh = 0; qh < 2; ++qh) {
    const u16* qrow = QKV + (size_t)(b * S + qbase + qh * 32 + l31) * LD + h * 64;
#pragma unroll
    for (int cc = 0; cc < 4; ++cc) qf[qh][cc] = *(const bf16x8*)(qrow + cc * 16 + lh * 8);
  }

  const int c0 = tid, c1 = tid + 256;
  const int r0 = c0 >> 3, x0 = ((c0 & 7) ^ (r0 & 7)) << 3;
  const int r1 = c1 >> 3, x1 = ((c1 & 7) ^ (r1 & 7)) << 3;
  const u16* Kbase = QKV + (size_t)b * S * LD + 1024 + h * 64;
  const u16* Vbase = Vtg + (size_t)bh * 64 * 2048;

#define STAGE(buf, kt_)                                                          \
  do {                                                                           \
    async16(Kbase + (size_t)((kt_)*64 + r0) * LD + x0, &Ks[buf][c0 * 8]);        \
    async16(Kbase + (size_t)((kt_)*64 + r1) * LD + x1, &Ks[buf][c1 * 8]);        \
    async16(Vbase + (size_t)r0 * 2048 + (kt_)*64 + x0, &Vs[buf][c0 * 8]);        \
    async16(Vbase + (size_t)r1 * 2048 + (kt_)*64 + x1, &Vs[buf][c1 * 8]);        \
  } while (0)

  f32x16 o00 = {}, o01 = {}, o10 = {}, o11 = {};
  float l0 = 0.f, l1 = 0.f;

#define TREE16(dst, arr)                                                         \
  do {                                                                           \
    float v_[16];                                                                \
    _Pragma("unroll") for (int r_ = 0; r_ < 16; ++r_) v_[r_] = (arr)[r_];        \
    _Pragma("unroll") for (int s_ = 8; s_ >= 1; s_ >>= 1)                        \
      _Pragma("unroll") for (int r_ = 0; r_ < s_; ++r_) v_[r_] += v_[r_ + s_];   \
    dst += v_[0];                                                                \
  } while (0)

#define MAKE_PA(pa, pk, q4)                                                      \
  bf16x8 pa;                                                                     \
  {                                                                              \
    u32x4 wv_;                                                                   \
    wv_[0] = (pk)[(q4) + 0];                                                     \
    wv_[1] = (pk)[(q4) + 1];                                                     \
    wv_[2] = (pk)[(q4) + 2];                                                     \
    wv_[3] = (pk)[(q4) + 3];                                                     \
    pa = __builtin_bit_cast(bf16x8, wv_);                                        \
  }

  STAGE(0, ktbeg);

  int cur = 0;
  for (int kt = ktbeg; kt < ktend; ++kt) {
    if (kt + 1 < ktend) {
      STAGE(cur ^ 1, kt + 1);
      asm volatile("s_waitcnt vmcnt(4)" ::: "memory");
    } else {
      asm volatile("s_waitcnt vmcnt(0)" ::: "memory");
    }
    __builtin_amdgcn_s_barrier();
    __builtin_amdgcn_sched_barrier(0);

    const bool active = (kt <= ktlast);
    if (active) {
      const bool full = (kt < ktlast);
      const u16* ks = Ks[cur];
      const u16* vs = Vs[cur];

      f32x16 t00, t10, t01, t11;
#pragma unroll
      for (int r = 0; r < 16; ++r) { t00[r] = -MFIX; t10[r] = -MFIX; t01[r] = -MFIX; t11[r] = -MFIX; }
      __builtin_amdgcn_s_setprio(1);
#pragma unroll
      for (int cc = 0; cc < 4; ++cc) {
        const int ci = 2 * cc + lh;
        const bf16x8 kf0 = *(const bf16x8*)&ks[l31 * 64 + ((ci ^ (l31 & 7)) << 3)];
        const bf16x8 kf1 = *(const bf16x8*)&ks[(32 + l31) * 64 + ((ci ^ (l31 & 7)) << 3)];
        t00 = __builtin_amdgcn_mfma_f32_32x32x16_bf16(kf0, qf[0][cc], t00, 0, 0, 0);
        t01 = __builtin_amdgcn_mfma_f32_32x32x16_bf16(kf0, qf[1][cc], t01, 0, 0, 0);
        if (full) t10 = __builtin_amdgcn_mfma_f32_32x32x16_bf16(kf1, qf[0][cc], t10, 0, 0, 0);
        t11 = __builtin_amdgcn_mfma_f32_32x32x16_bf16(kf1, qf[1][cc], t11, 0, 0, 0);
      }
      __builtin_amdgcn_s_setprio(0);

      if (!full) {
#pragma unroll
        for (int r = 0; r < 16; ++r) {
          const int ko = (r & 3) + 8 * (r >> 2) + 4 * lh;
          if (ko > l31) { t00[r] = -3e38f; t11[r] = -3e38f; }
        }
      }

      u32 pk0[8], pk1[8];

#pragma unroll
      for (int r = 0; r < 16; ++r) t00[r] = exp2f(t00[r]);
#pragma unroll
      for (int r = 0; r < 16; ++r) t01[r] = exp2f(t01[r]);
      TREE16(l0, t00);
      TREE16(l1, t01);
#pragma unroll
      for (int j = 0; j < 8; ++j) {
        pk0[j] = packbf(t00[2 * j], t00[2 * j + 1]);
        pk1[j] = packbf(t01[2 * j], t01[2 * j + 1]);
      }
      __builtin_amdgcn_s_setprio(1);
#pragma unroll
      for (int kc = 0; kc < 2; ++kc) {
        const int q4 = kc * 4;
        MAKE_PA(pa0, pk0, q4)
        MAKE_PA(pa1, pk1, q4)
        const int ci = 2 * kc + lh;
        const bf16x8 vd0 = *(const bf16x8*)&vs[l31 * 64 + ((ci ^ (l31 & 7)) << 3)];
        const bf16x8 vd1 = *(const bf16x8*)&vs[(32 + l31) * 64 + ((ci ^ (l31 & 7)) << 3)];
        o00 = __builtin_amdgcn_mfma_f32_32x32x16_bf16(pa0, vd0, o00, 0, 0, 0);
        o01 = __builtin_amdgcn_mfma_f32_32x32x16_bf16(pa0, vd1, o01, 0, 0, 0);
        o10 = __builtin_amdgcn_mfma_f32_32x32x16_bf16(pa1, vd0, o10, 0, 0, 0);
        o11 = __builtin_amdgcn_mfma_f32_32x32x16_bf16(pa1, vd1, o11, 0, 0, 0);
      }
      __builtin_amdgcn_s_setprio(0);

      if (full) {
#pragma unroll
        for (int r = 0; r < 16; ++r) t10[r] = exp2f(t10[r]);
        TREE16(l0, t10);
#pragma unroll
        for (int j = 0; j < 8; ++j) pk0[j] = packbf(t10[2 * j], t10[2 * j + 1]);
      }
#pragma unroll
      for (int r = 0; r < 16; ++r) t11[r] = exp2f(t11[r]);
      TREE16(l1, t11);
#pragma unroll
      for (int j = 0; j < 8; ++j) pk1[j] = packbf(t11[2 * j], t11[2 * j + 1]);

      __builtin_amdgcn_s_setprio(1);
#pragma unroll
      for (int kc = 0; kc < 2; ++kc) {
        const int q4 = kc * 4;
        MAKE_PA(pa1, pk1, q4)
        const int ci = 2 * (kc + 2) + lh;
        const bf16x8 vd0 = *(const bf16x8*)&vs[l31 * 64 + ((ci ^ (l31 & 7)) << 3)];
        const bf16x8 vd1 = *(const bf16x8*)&vs[(32 + l31) * 64 + ((ci ^ (l31 & 7)) << 3)];
        if (full) {
          MAKE_PA(pa0, pk0, q4)
          o00 = __builtin_amdgcn_mfma_f32_32x32x16_bf16(pa0, vd0, o00, 0, 0, 0);
          o01 = __builtin_amdgcn_mfma_f32_32x32x16_bf16(pa0, vd1, o01, 0, 0, 0);
        }
        o10 = __builtin_amdgcn_mfma_f32_32x32x16_bf16(pa1, vd0, o10, 0, 0, 0);
        o11 = __builtin_amdgcn_mfma_f32_32x32x16_bf16(pa1, vd1, o11, 0, 0, 0);
      }
      __builtin_amdgcn_s_setprio(0);
    }

    asm volatile("s_waitcnt lgkmcnt(0)" ::: "memory");
    __builtin_amdgcn_s_barrier();
    cur ^= 1;
  }
#undef STAGE
#undef TREE16
#undef MAKE_PA

  const float l0t = l0 + __shfl_xor(l0, 32);
  const float l1t = l1 + __shfl_xor(l1, 32);
  u16* Oc = Opart + (size_t)c * 4096 * 1024;
#pragma unroll
  for (int r = 0; r < 16; ++r) {
    const int qo = (r & 3) + 8 * (r >> 2) + 4 * lh;
    u16* p0 = Oc + (size_t)(b * S + qbase + qo) * 1024 + h * 64 + l31;
    u16* p1 = p0 + (size_t)32 * 1024;
    p0[0] = f2bf(o00[r]);
    p0[32] = f2bf(o01[r]);
    p1[0] = f2bf(o10[r]);
    p1[32] = f2bf(o11[r]);
  }
  if (lh == 0) {
    Lpart[(size_t)c * 4096 * 16 + (size_t)(b * S + qbase + l31) * 16 + h] = l0t;
    Lpart[(size_t)c * 4096 * 16 + (size_t)(b * S + qbase + 32 + l31) * 16 + h] = l1t;
  }
}

extern "C" void kernel_launch(void* const* d_in, const int* in_sizes, int n_in,
                              void* d_out, int out_size, void* d_ws, size_t ws_size,
                              hipStream_t stream) {
  const float* x  = (const float*)d_in[0];
  const float* WQ = (const float*)d_in[1];
  const float* WK = (const float*)d_in[2];
  const float* WV = (const float*)d_in[3];
  const float* WO = (const float*)d_in[4];
  float* out = (float*)d_out;

  u16* xb    = (u16*)d_ws;                      // 4096*1024
  u16* WtQKV = xb + (size_t)4096 * 1024;        // 3072*1024
  u16* WtO   = WtQKV + (size_t)3072 * 1024;     // 1024*1024
  u16* QKV   = WtO + (size_t)1024 * 1024;       // 4096*3072
  u16* Vtg   = QKV + (size_t)4096 * 3072;       // 2048*2048
  u16* Opart = Vtg + (size_t)2048 * 2048;       // 2 * 4096*1024 bf16
  float* Lpart = (float*)(Opart + (size_t)2 * 4096 * 1024);  // 2 * 4096*16 f32

  prep<<<dim3(32, 32, 5), 256, 0, stream>>>(x, xb, WQ, WK, WV, WO, WtQKV, WtO);

  gemm_qkv<<<dim3(32, 24), 256, 0, stream>>>(xb, WtQKV, QKV, Vtg);
  attn_kernel<<<dim3(16, 32), 256, 0, stream>>>(QKV, Vtg, Opart, Lpart);
  gemm_out<<<dim3(32, 8), 256, 0, stream>>>(Opart, Lpart, WtO, out);
}

// Round 20
// 138.448 us; speedup vs baseline: 1.1998x; 1.1998x over previous
//
#include <hip/hip_runtime.h>

typedef unsigned short u16;
typedef unsigned int u32;
typedef __attribute__((ext_vector_type(8))) __bf16 bf16x8;
typedef __attribute__((ext_vector_type(2))) __bf16 bf16x2;
typedef __attribute__((ext_vector_type(4))) float f32x4;
typedef __attribute__((ext_vector_type(16))) float f32x16;
typedef __attribute__((ext_vector_type(4))) u32 u32x4;

__device__ inline u16 f2bf(float f) {
  unsigned u = __builtin_bit_cast(unsigned, f);
  u += 0x7FFFu + ((u >> 16) & 1u);
  return (u16)(u >> 16);
}

__device__ inline u32 packbf(float a, float b) {
  bf16x2 t;
  t[0] = (__bf16)a;
  t[1] = (__bf16)b;
  return __builtin_bit_cast(u32, t);
}

__device__ inline void async16(const void* g, void* l) {
  __builtin_amdgcn_global_load_lds((const __attribute__((address_space(1))) void*)g,
                                   (__attribute__((address_space(3))) void*)l, 16, 0, 0);
}

// ---------------- fused prep: x fp32->bf16 (z==4) + 4x weight transpose (z<4) ----------------
// z==0 (W_Q) folds 0.125*log2(e) so QK^T comes out in exp2 domain.
__global__ __launch_bounds__(256) void prep(const float* __restrict__ x, u16* __restrict__ xb,
                                            const float* __restrict__ W0,
                                            const float* __restrict__ W1,
                                            const float* __restrict__ W2,
                                            const float* __restrict__ W3,
                                            u16* __restrict__ WtQKV,
                                            u16* __restrict__ WtO) {
  const int z = blockIdx.z;
  if (z == 4) {
    const int base = (blockIdx.y * 32 + blockIdx.x) * 4 * 256 + threadIdx.x;
#pragma unroll
    for (int it = 0; it < 4; ++it) {
      const int i = base + it * 256;
      float4 v = ((const float4*)x)[i];
      ushort4 r;
      r.x = f2bf(v.x); r.y = f2bf(v.y); r.z = f2bf(v.z); r.w = f2bf(v.w);
      ((ushort4*)xb)[i] = r;
    }
    return;
  }
  __shared__ u16 tile[32][33];
  const float* W = (z == 0) ? W0 : (z == 1) ? W1 : (z == 2) ? W2 : W3;
  u16* Wt = (z < 3) ? (WtQKV + (size_t)z * 1024 * 1024) : WtO;
  const float s = (z == 0) ? 0.18033688011112042f : 1.0f;
  const int e0 = blockIdx.x * 32;
  const int d0 = blockIdx.y * 32;
  const int tx = threadIdx.x & 31;
  const int ty = threadIdx.x >> 5;
#pragma unroll
  for (int i = ty; i < 32; i += 8)
    tile[i][tx] = f2bf(W[(size_t)(d0 + i) * 1024 + e0 + tx] * s);
  __syncthreads();
#pragma unroll
  for (int i = ty; i < 32; i += 8)
    Wt[(size_t)(e0 + i) * 1024 + d0 + tx] = tile[tx][i];
}

// ---------------- GEMM C[M,N] = A[M,K] * Bt[N,K]^T  (m97 structure + XCD swizzle) ----------------
// FUSE_V: for output cols >= 2048 (the V slice of QKV) also write sigma-permuted transposed
// copy into Vtg[b*1024+dg][sigma(s)] -- bit-identical to the standalone vtrans kernel.
template <int OUT_BF16, int FUSE_V>
__global__ __launch_bounds__(256) void gemm_bt(const u16* __restrict__ A,
                                               const u16* __restrict__ Bt,
                                               void* __restrict__ Cp,
                                               u16* __restrict__ Vtg,
                                               int M, int N, int K) {
  __shared__ __align__(16) u16 As[128 * 32];
  __shared__ __align__(16) u16 Bs[128 * 32];
  const int tid = threadIdx.x;
  const int lane = tid & 63;
  const int wave = tid >> 6;
  const int lr = lane & 15;
  const int lk = (lane >> 4) * 8;
  const int wm = (wave >> 1) * 64;
  const int wn = (wave & 1) * 64;

  // chunked XCD swizzle (bijective: nwg % 8 == 0 for both call sites)
  const int flat = blockIdx.y * gridDim.x + blockIdx.x;
  const int chunk = (gridDim.x * gridDim.y) >> 3;
  const int nf = (flat & 7) * chunk + (flat >> 3);
  const int bm = (nf % gridDim.x) * 128;
  const int bn = (nf / gridDim.x) * 128;

  const int srow = lane >> 2;
  const int scol = (lane & 3) * 8;

  f32x4 acc[4][4] = {};

  for (int k0 = 0; k0 < K; k0 += 32) {
#pragma unroll
    for (int r = 0; r < 2; ++r) {
      const int chnk = r * 4 + wave;
      const int row = chnk * 16 + srow;
      async16(A + (size_t)(bm + row) * K + k0 + scol, &As[chnk * 512 + lane * 8]);
      async16(Bt + (size_t)(bn + row) * K + k0 + scol, &Bs[chnk * 512 + lane * 8]);
    }
    __syncthreads();
    bf16x8 a[4], b[4];
#pragma unroll
    for (int i = 0; i < 4; ++i) {
      a[i] = *(const bf16x8*)&As[(wm + i * 16 + lr) * 32 + lk];
      b[i] = *(const bf16x8*)&Bs[(wn + i * 16 + lr) * 32 + lk];
    }
#pragma unroll
    for (int mi = 0; mi < 4; ++mi)
#pragma unroll
      for (int ni = 0; ni < 4; ++ni)
        acc[mi][ni] = __builtin_amdgcn_mfma_f32_16x16x32_bf16(a[mi], b[ni], acc[mi][ni], 0, 0, 0);
    __syncthreads();
  }

#pragma unroll
  for (int mi = 0; mi < 4; ++mi) {
    const int row = bm + wm + mi * 16 + (lane >> 4) * 4;   // j=0 row; j spans row..row+3
#pragma unroll
    for (int ni = 0; ni < 4; ++ni) {
      const int col = bn + wn + ni * 16 + lr;
#pragma unroll
      for (int j = 0; j < 4; ++j) {
        if (OUT_BF16)
          ((u16*)Cp)[(size_t)(row + j) * N + col] = f2bf(acc[mi][ni][j]);
        else
          ((float*)Cp)[(size_t)(row + j) * N + col] = acc[mi][ni][j];
      }
      if (FUSE_V && col >= 2048) {
        const int bloc = row >> 11;
        const int s = row & 2047;
        const int sp = (s & ~12) | ((s & 4) << 1) | ((s & 8) >> 1);  // sigma: swap bits 2,3
        ushort4 v4;
        v4.x = f2bf(acc[mi][ni][0]);
        v4.y = f2bf(acc[mi][ni][1]);
        v4.z = f2bf(acc[mi][ni][2]);
        v4.w = f2bf(acc[mi][ni][3]);
        *(ushort4*)(Vtg + (size_t)(bloc * 1024 + (col - 2048)) * 2048 + sp) = v4;
      }
    }
  }
}

// ---------------- Flash causal attention (R17 proven: 55.8us) ----------------
// 64 q/wave, shuffle-free PV via sigma-permuted V, KV-split=2, fixed-m softmax, counted
// vmcnt(4), chunked XCD swizzle (each XCD owns 4 bh -> 2MB KV working set in its L2).
__global__ __launch_bounds__(256, 2) void attn_kernel(const u16* __restrict__ QKV,
                                                      const u16* __restrict__ Vtg,
                                                      u16* __restrict__ Opart,
                                                      float* __restrict__ Lpart) {
  constexpr int S = 2048, LD = 3072;
  constexpr float MFIX = 12.0f;
  __shared__ __align__(16) u16 Ks[2][64 * 64];
  __shared__ __align__(16) u16 Vs[2][64 * 64];

  const int flat = blockIdx.y * 16 + blockIdx.x;
  const int nf = (flat & 7) * 64 + (flat >> 3);
  const int xi = nf & 15;
  const int bh = nf >> 4;

  const int g = 7 - (xi >> 1);
  const int c = xi & 1;
  const int b = bh >> 4, h = bh & 15;
  const int tid = threadIdx.x, lane = tid & 63, w = tid >> 6;
  const int l31 = lane & 31, lh = lane >> 5;

  const int qbase = g * 256 + w * 64;
  const int ktlast = 4 * g + w;
  const int ktbeg = c * (2 * g + 2);
  const int ktend = (c + 1) * (2 * g + 2);

  bf16x8 qf[2][4];
#pragma unroll
  for (int qh = 0; qh < 2; ++qh) {
    const u16* qrow = QKV + (size_t)(b * S + qbase + qh * 32 + l31) * LD + h * 64;
#pragma unroll
    for (int cc = 0; cc < 4; ++cc) qf[qh][cc] = *(const bf16x8*)(qrow + cc * 16 + lh * 8);
  }

  const int c0 = tid, c1 = tid + 256;
  const int r0 = c0 >> 3, x0 = ((c0 & 7) ^ (r0 & 7)) << 3;
  const int r1 = c1 >> 3, x1 = ((c1 & 7) ^ (r1 & 7)) << 3;
  const u16* Kbase = QKV + (size_t)b * S * LD + 1024 + h * 64;
  const u16* Vbase = Vtg + (size_t)bh * 64 * 2048;

#define STAGE(buf, kt_)                                                          \
  do {                                                                           \
    async16(Kbase + (size_t)((kt_)*64 + r0) * LD + x0, &Ks[buf][c0 * 8]);        \
    async16(Kbase + (size_t)((kt_)*64 + r1) * LD + x1, &Ks[buf][c1 * 8]);        \
    async16(Vbase + (size_t)r0 * 2048 + (kt_)*64 + x0, &Vs[buf][c0 * 8]);        \
    async16(Vbase + (size_t)r1 * 2048 + (kt_)*64 + x1, &Vs[buf][c1 * 8]);        \
  } while (0)

  f32x16 o00 = {}, o01 = {}, o10 = {}, o11 = {};
  float l0 = 0.f, l1 = 0.f;

#define TREE16(dst, arr)                                                         \
  do {                                                                           \
    float v_[16];                                                                \
    _Pragma("unroll") for (int r_ = 0; r_ < 16; ++r_) v_[r_] = (arr)[r_];        \
    _Pragma("unroll") for (int s_ = 8; s_ >= 1; s_ >>= 1)                        \
      _Pragma("unroll") for (int r_ = 0; r_ < s_; ++r_) v_[r_] += v_[r_ + s_];   \
    dst += v_[0];                                                                \
  } while (0)

#define MAKE_PA(pa, pk, q4)                                                      \
  bf16x8 pa;                                                                     \
  {                                                                              \
    u32x4 wv_;                                                                   \
    wv_[0] = (pk)[(q4) + 0];                                                     \
    wv_[1] = (pk)[(q4) + 1];                                                     \
    wv_[2] = (pk)[(q4) + 2];                                                     \
    wv_[3] = (pk)[(q4) + 3];                                                     \
    pa = __builtin_bit_cast(bf16x8, wv_);                                        \
  }

  STAGE(0, ktbeg);

  int cur = 0;
  for (int kt = ktbeg; kt < ktend; ++kt) {
    if (kt + 1 < ktend) {
      STAGE(cur ^ 1, kt + 1);
      asm volatile("s_waitcnt vmcnt(4)" ::: "memory");
    } else {
      asm volatile("s_waitcnt vmcnt(0)" ::: "memory");
    }
    __builtin_amdgcn_s_barrier();
    __builtin_amdgcn_sched_barrier(0);

    const bool active = (kt <= ktlast);
    if (active) {
      const bool full = (kt < ktlast);
      const u16* ks = Ks[cur];
      const u16* vs = Vs[cur];

      f32x16 t00 = {}, t10 = {}, t01 = {}, t11 = {};
      __builtin_amdgcn_s_setprio(1);
#pragma unroll
      for (int cc = 0; cc < 4; ++cc) {
        const int ci = 2 * cc + lh;
        const bf16x8 kf0 = *(const bf16x8*)&ks[l31 * 64 + ((ci ^ (l31 & 7)) << 3)];
        const bf16x8 kf1 = *(const bf16x8*)&ks[(32 + l31) * 64 + ((ci ^ (l31 & 7)) << 3)];
        t00 = __builtin_amdgcn_mfma_f32_32x32x16_bf16(kf0, qf[0][cc], t00, 0, 0, 0);
        t01 = __builtin_amdgcn_mfma_f32_32x32x16_bf16(kf0, qf[1][cc], t01, 0, 0, 0);
        if (full) t10 = __builtin_amdgcn_mfma_f32_32x32x16_bf16(kf1, qf[0][cc], t10, 0, 0, 0);
        t11 = __builtin_amdgcn_mfma_f32_32x32x16_bf16(kf1, qf[1][cc], t11, 0, 0, 0);
      }
      __builtin_amdgcn_s_setprio(0);

      if (!full) {
#pragma unroll
        for (int r = 0; r < 16; ++r) {
          const int ko = (r & 3) + 8 * (r >> 2) + 4 * lh;
          if (ko > l31) { t00[r] = -3e38f; t11[r] = -3e38f; }
        }
      }

      u32 pk0[8], pk1[8];

#pragma unroll
      for (int r = 0; r < 16; ++r) t00[r] = exp2f(t00[r] - MFIX);
#pragma unroll
      for (int r = 0; r < 16; ++r) t01[r] = exp2f(t01[r] - MFIX);
      TREE16(l0, t00);
      TREE16(l1, t01);
#pragma unroll
      for (int j = 0; j < 8; ++j) {
        pk0[j] = packbf(t00[2 * j], t00[2 * j + 1]);
        pk1[j] = packbf(t01[2 * j], t01[2 * j + 1]);
      }
      __builtin_amdgcn_s_setprio(1);
#pragma unroll
      for (int kc = 0; kc < 2; ++kc) {
        const int q4 = kc * 4;
        MAKE_PA(pa0, pk0, q4)
        MAKE_PA(pa1, pk1, q4)
        const int ci = 2 * kc + lh;
        const bf16x8 vd0 = *(const bf16x8*)&vs[l31 * 64 + ((ci ^ (l31 & 7)) << 3)];
        const bf16x8 vd1 = *(const bf16x8*)&vs[(32 + l31) * 64 + ((ci ^ (l31 & 7)) << 3)];
        o00 = __builtin_amdgcn_mfma_f32_32x32x16_bf16(pa0, vd0, o00, 0, 0, 0);
        o01 = __builtin_amdgcn_mfma_f32_32x32x16_bf16(pa0, vd1, o01, 0, 0, 0);
        o10 = __builtin_amdgcn_mfma_f32_32x32x16_bf16(pa1, vd0, o10, 0, 0, 0);
        o11 = __builtin_amdgcn_mfma_f32_32x32x16_bf16(pa1, vd1, o11, 0, 0, 0);
      }
      __builtin_amdgcn_s_setprio(0);

      if (full) {
#pragma unroll
        for (int r = 0; r < 16; ++r) t10[r] = exp2f(t10[r] - MFIX);
        TREE16(l0, t10);
#pragma unroll
        for (int j = 0; j < 8; ++j) pk0[j] = packbf(t10[2 * j], t10[2 * j + 1]);
      }
#pragma unroll
      for (int r = 0; r < 16; ++r) t11[r] = exp2f(t11[r] - MFIX);
      TREE16(l1, t11);
#pragma unroll
      for (int j = 0; j < 8; ++j) pk1[j] = packbf(t11[2 * j], t11[2 * j + 1]);

      __builtin_amdgcn_s_setprio(1);
#pragma unroll
      for (int kc = 0; kc < 2; ++kc) {
        const int q4 = kc * 4;
        MAKE_PA(pa1, pk1, q4)
        const int ci = 2 * (kc + 2) + lh;
        const bf16x8 vd0 = *(const bf16x8*)&vs[l31 * 64 + ((ci ^ (l31 & 7)) << 3)];
        const bf16x8 vd1 = *(const bf16x8*)&vs[(32 + l31) * 64 + ((ci ^ (l31 & 7)) << 3)];
        if (full) {
          MAKE_PA(pa0, pk0, q4)
          o00 = __builtin_amdgcn_mfma_f32_32x32x16_bf16(pa0, vd0, o00, 0, 0, 0);
          o01 = __builtin_amdgcn_mfma_f32_32x32x16_bf16(pa0, vd1, o01, 0, 0, 0);
        }
        o10 = __builtin_amdgcn_mfma_f32_32x32x16_bf16(pa1, vd0, o10, 0, 0, 0);
        o11 = __builtin_amdgcn_mfma_f32_32x32x16_bf16(pa1, vd1, o11, 0, 0, 0);
      }
      __builtin_amdgcn_s_setprio(0);
    }

    asm volatile("s_waitcnt lgkmcnt(0)" ::: "memory");
    __builtin_amdgcn_s_barrier();
    cur ^= 1;
  }
#undef STAGE
#undef TREE16
#undef MAKE_PA

  const float l0t = l0 + __shfl_xor(l0, 32);
  const float l1t = l1 + __shfl_xor(l1, 32);
  u16* Oc = Opart + (size_t)c * 4096 * 1024;
#pragma unroll
  for (int r = 0; r < 16; ++r) {
    const int qo = (r & 3) + 8 * (r >> 2) + 4 * lh;
    u16* p0 = Oc + (size_t)(b * S + qbase + qo) * 1024 + h * 64 + l31;
    u16* p1 = p0 + (size_t)32 * 1024;
    p0[0] = f2bf(o00[r]);
    p0[32] = f2bf(o01[r]);
    p1[0] = f2bf(o10[r]);
    p1[32] = f2bf(o11[r]);
  }
  if (lh == 0) {
    Lpart[(size_t)c * 4096 * 16 + (size_t)(b * S + qbase + l31) * 16 + h] = l0t;
    Lpart[(size_t)c * 4096 * 16 + (size_t)(b * S + qbase + 32 + l31) * 16 + h] = l1t;
  }
}

// ---------------- combine partials: Obuf = (O0 + O1) / (l0 + l1) ----------------
__global__ __launch_bounds__(256) void combine(const u16* __restrict__ Opart,
                                               const float* __restrict__ Lpart,
                                               u16* __restrict__ Obuf) {
  const int i = blockIdx.x * 256 + threadIdx.x;
  const int row = i >> 7;
  const int cw = (i & 127) * 8;
  const int h = cw >> 6;
  const float l = Lpart[(size_t)row * 16 + h] + Lpart[(size_t)4096 * 16 + (size_t)row * 16 + h];
  const float inv = 1.0f / l;
  const bf16x8 a = *(const bf16x8*)(Opart + (size_t)row * 1024 + cw);
  const bf16x8 bq = *(const bf16x8*)(Opart + (size_t)4096 * 1024 + (size_t)row * 1024 + cw);
  u16 out[8];
#pragma unroll
  for (int j = 0; j < 8; ++j) out[j] = f2bf(((float)a[j] + (float)bq[j]) * inv);
  *(uint4*)(Obuf + (size_t)row * 1024 + cw) = *(uint4*)out;
}

extern "C" void kernel_launch(void* const* d_in, const int* in_sizes, int n_in,
                              void* d_out, int out_size, void* d_ws, size_t ws_size,
                              hipStream_t stream) {
  const float* x  = (const float*)d_in[0];
  const float* WQ = (const float*)d_in[1];
  const float* WK = (const float*)d_in[2];
  const float* WV = (const float*)d_in[3];
  const float* WO = (const float*)d_in[4];
  float* out = (float*)d_out;

  u16* xb    = (u16*)d_ws;                      // 4096*1024
  u16* WtQKV = xb + (size_t)4096 * 1024;        // 3072*1024
  u16* WtO   = WtQKV + (size_t)3072 * 1024;     // 1024*1024
  u16* QKV   = WtO + (size_t)1024 * 1024;       // 4096*3072
  u16* Obuf  = QKV + (size_t)4096 * 3072;       // 4096*1024
  u16* Vtg   = Obuf + (size_t)4096 * 1024;      // 2048*2048
  u16* Opart = Vtg + (size_t)2048 * 2048;       // 2 * 4096*1024 bf16
  float* Lpart = (float*)(Opart + (size_t)2 * 4096 * 1024);  // 2 * 4096*16 f32

  prep<<<dim3(32, 32, 5), 256, 0, stream>>>(x, xb, WQ, WK, WV, WO, WtQKV, WtO);

  gemm_bt<1, 1><<<dim3(32, 24), 256, 0, stream>>>(xb, WtQKV, QKV, Vtg, 4096, 3072, 1024);
  attn_kernel<<<dim3(16, 32), 256, 0, stream>>>(QKV, Vtg, Opart, Lpart);
  combine<<<2048, 256, 0, stream>>>(Opart, Lpart, Obuf);
  gemm_bt<0, 0><<<dim3(32, 8), 256, 0, stream>>>(Obuf, WtO, out, nullptr, 4096, 1024, 1024);
}

// Round 21
// 138.191 us; speedup vs baseline: 1.2020x; 1.0019x over previous
//
#include <hip/hip_runtime.h>

typedef unsigned short u16;
typedef unsigned int u32;
typedef __attribute__((ext_vector_type(8))) __bf16 bf16x8;
typedef __attribute__((ext_vector_type(2))) __bf16 bf16x2;
typedef __attribute__((ext_vector_type(4))) float f32x4;
typedef __attribute__((ext_vector_type(16))) float f32x16;
typedef __attribute__((ext_vector_type(4))) u32 u32x4;

__device__ inline u16 f2bf(float f) {
  unsigned u = __builtin_bit_cast(unsigned, f);
  u += 0x7FFFu + ((u >> 16) & 1u);
  return (u16)(u >> 16);
}

__device__ inline u32 packbf(float a, float b) {
  bf16x2 t;
  t[0] = (__bf16)a;
  t[1] = (__bf16)b;
  return __builtin_bit_cast(u32, t);
}

__device__ inline void async16(const void* g, void* l) {
  __builtin_amdgcn_global_load_lds((const __attribute__((address_space(1))) void*)g,
                                   (__attribute__((address_space(3))) void*)l, 16, 0, 0);
}

// ---------------- fused prep: x fp32->bf16 (z==4) + 4x weight transpose (z<4) ----------------
// z==0 (W_Q) folds 0.125*log2(e) so QK^T comes out in exp2 domain.
__global__ __launch_bounds__(256) void prep(const float* __restrict__ x, u16* __restrict__ xb,
                                            const float* __restrict__ W0,
                                            const float* __restrict__ W1,
                                            const float* __restrict__ W2,
                                            const float* __restrict__ W3,
                                            u16* __restrict__ WtQKV,
                                            u16* __restrict__ WtO) {
  const int z = blockIdx.z;
  if (z == 4) {
    const int base = (blockIdx.y * 32 + blockIdx.x) * 4 * 256 + threadIdx.x;
#pragma unroll
    for (int it = 0; it < 4; ++it) {
      const int i = base + it * 256;
      float4 v = ((const float4*)x)[i];
      ushort4 r;
      r.x = f2bf(v.x); r.y = f2bf(v.y); r.z = f2bf(v.z); r.w = f2bf(v.w);
      ((ushort4*)xb)[i] = r;
    }
    return;
  }
  __shared__ u16 tile[32][33];
  const float* W = (z == 0) ? W0 : (z == 1) ? W1 : (z == 2) ? W2 : W3;
  u16* Wt = (z < 3) ? (WtQKV + (size_t)z * 1024 * 1024) : WtO;
  const float s = (z == 0) ? 0.18033688011112042f : 1.0f;
  const int e0 = blockIdx.x * 32;
  const int d0 = blockIdx.y * 32;
  const int tx = threadIdx.x & 31;
  const int ty = threadIdx.x >> 5;
#pragma unroll
  for (int i = ty; i < 32; i += 8)
    tile[i][tx] = f2bf(W[(size_t)(d0 + i) * 1024 + e0 + tx] * s);
  __syncthreads();
#pragma unroll
  for (int i = ty; i < 32; i += 8)
    Wt[(size_t)(e0 + i) * 1024 + d0 + tx] = tile[tx][i];
}

// ---------------- GEMM C[M,N] = A[M,K] * Bt[N,K]^T  (m97 structure + XCD swizzle) ----------------
// FUSE_V: for output cols >= 2048 (the V slice of QKV) also write sigma-permuted transposed
// copy into Vtg[b*1024+dg][sigma(s)] -- bit-identical to the standalone vtrans kernel.
template <int OUT_BF16, int FUSE_V>
__global__ __launch_bounds__(256) void gemm_bt(const u16* __restrict__ A,
                                               const u16* __restrict__ Bt,
                                               void* __restrict__ Cp,
                                               u16* __restrict__ Vtg,
                                               int M, int N, int K) {
  __shared__ __align__(16) u16 As[128 * 32];
  __shared__ __align__(16) u16 Bs[128 * 32];
  const int tid = threadIdx.x;
  const int lane = tid & 63;
  const int wave = tid >> 6;
  const int lr = lane & 15;
  const int lk = (lane >> 4) * 8;
  const int wm = (wave >> 1) * 64;
  const int wn = (wave & 1) * 64;

  // chunked XCD swizzle (bijective: nwg % 8 == 0 for both call sites)
  const int flat = blockIdx.y * gridDim.x + blockIdx.x;
  const int chunk = (gridDim.x * gridDim.y) >> 3;
  const int nf = (flat & 7) * chunk + (flat >> 3);
  const int bm = (nf % gridDim.x) * 128;
  const int bn = (nf / gridDim.x) * 128;

  const int srow = lane >> 2;
  const int scol = (lane & 3) * 8;

  f32x4 acc[4][4] = {};

  for (int k0 = 0; k0 < K; k0 += 32) {
#pragma unroll
    for (int r = 0; r < 2; ++r) {
      const int chnk = r * 4 + wave;
      const int row = chnk * 16 + srow;
      async16(A + (size_t)(bm + row) * K + k0 + scol, &As[chnk * 512 + lane * 8]);
      async16(Bt + (size_t)(bn + row) * K + k0 + scol, &Bs[chnk * 512 + lane * 8]);
    }
    __syncthreads();
    bf16x8 a[4], b[4];
#pragma unroll
    for (int i = 0; i < 4; ++i) {
      a[i] = *(const bf16x8*)&As[(wm + i * 16 + lr) * 32 + lk];
      b[i] = *(const bf16x8*)&Bs[(wn + i * 16 + lr) * 32 + lk];
    }
#pragma unroll
    for (int mi = 0; mi < 4; ++mi)
#pragma unroll
      for (int ni = 0; ni < 4; ++ni)
        acc[mi][ni] = __builtin_amdgcn_mfma_f32_16x16x32_bf16(a[mi], b[ni], acc[mi][ni], 0, 0, 0);
    __syncthreads();
  }

#pragma unroll
  for (int mi = 0; mi < 4; ++mi) {
    const int row = bm + wm + mi * 16 + (lane >> 4) * 4;   // j=0 row; j spans row..row+3
#pragma unroll
    for (int ni = 0; ni < 4; ++ni) {
      const int col = bn + wn + ni * 16 + lr;
#pragma unroll
      for (int j = 0; j < 4; ++j) {
        if (OUT_BF16)
          ((u16*)Cp)[(size_t)(row + j) * N + col] = f2bf(acc[mi][ni][j]);
        else
          ((float*)Cp)[(size_t)(row + j) * N + col] = acc[mi][ni][j];
      }
      if (FUSE_V && col >= 2048) {
        const int bloc = row >> 11;
        const int s = row & 2047;
        const int sp = (s & ~12) | ((s & 4) << 1) | ((s & 8) >> 1);  // sigma: swap bits 2,3
        ushort4 v4;
        v4.x = f2bf(acc[mi][ni][0]);
        v4.y = f2bf(acc[mi][ni][1]);
        v4.z = f2bf(acc[mi][ni][2]);
        v4.w = f2bf(acc[mi][ni][3]);
        *(ushort4*)(Vtg + (size_t)(bloc * 1024 + (col - 2048)) * 2048 + sp) = v4;
      }
    }
  }
}

// ---------------- Flash causal attention (proven: 55.8us) ----------------
// 64 q/wave, shuffle-free PV via sigma-permuted V, KV-split=2, fixed-m softmax, counted
// vmcnt(4), chunked XCD swizzle (each XCD owns 4 bh -> 2MB KV working set in its L2).
__global__ __launch_bounds__(256, 2) void attn_kernel(const u16* __restrict__ QKV,
                                                      const u16* __restrict__ Vtg,
                                                      u16* __restrict__ Opart,
                                                      float* __restrict__ Lpart) {
  constexpr int S = 2048, LD = 3072;
  constexpr float MFIX = 12.0f;
  __shared__ __align__(16) u16 Ks[2][64 * 64];
  __shared__ __align__(16) u16 Vs[2][64 * 64];

  const int flat = blockIdx.y * 16 + blockIdx.x;
  const int nf = (flat & 7) * 64 + (flat >> 3);
  const int xi = nf & 15;
  const int bh = nf >> 4;

  const int g = 7 - (xi >> 1);
  const int c = xi & 1;
  const int b = bh >> 4, h = bh & 15;
  const int tid = threadIdx.x, lane = tid & 63, w = tid >> 6;
  const int l31 = lane & 31, lh = lane >> 5;

  const int qbase = g * 256 + w * 64;
  const int ktlast = 4 * g + w;
  const int ktbeg = c * (2 * g + 2);
  const int ktend = (c + 1) * (2 * g + 2);

  bf16x8 qf[2][4];
#pragma unroll
  for (int qh = 0; qh < 2; ++qh) {
    const u16* qrow = QKV + (size_t)(b * S + qbase + qh * 32 + l31) * LD + h * 64;
#pragma unroll
    for (int cc = 0; cc < 4; ++cc) qf[qh][cc] = *(const bf16x8*)(qrow + cc * 16 + lh * 8);
  }

  const int c0 = tid, c1 = tid + 256;
  const int r0 = c0 >> 3, x0 = ((c0 & 7) ^ (r0 & 7)) << 3;
  const int r1 = c1 >> 3, x1 = ((c1 & 7) ^ (r1 & 7)) << 3;
  const u16* Kbase = QKV + (size_t)b * S * LD + 1024 + h * 64;
  const u16* Vbase = Vtg + (size_t)bh * 64 * 2048;

#define STAGE(buf, kt_)                                                          \
  do {                                                                           \
    async16(Kbase + (size_t)((kt_)*64 + r0) * LD + x0, &Ks[buf][c0 * 8]);        \
    async16(Kbase + (size_t)((kt_)*64 + r1) * LD + x1, &Ks[buf][c1 * 8]);        \
    async16(Vbase + (size_t)r0 * 2048 + (kt_)*64 + x0, &Vs[buf][c0 * 8]);        \
    async16(Vbase + (size_t)r1 * 2048 + (kt_)*64 + x1, &Vs[buf][c1 * 8]);        \
  } while (0)

  f32x16 o00 = {}, o01 = {}, o10 = {}, o11 = {};
  float l0 = 0.f, l1 = 0.f;

#define TREE16(dst, arr)                                                         \
  do {                                                                           \
    float v_[16];                                                                \
    _Pragma("unroll") for (int r_ = 0; r_ < 16; ++r_) v_[r_] = (arr)[r_];        \
    _Pragma("unroll") for (int s_ = 8; s_ >= 1; s_ >>= 1)                        \
      _Pragma("unroll") for (int r_ = 0; r_ < s_; ++r_) v_[r_] += v_[r_ + s_];   \
    dst += v_[0];                                                                \
  } while (0)

#define MAKE_PA(pa, pk, q4)                                                      \
  bf16x8 pa;                                                                     \
  {                                                                              \
    u32x4 wv_;                                                                   \
    wv_[0] = (pk)[(q4) + 0];                                                     \
    wv_[1] = (pk)[(q4) + 1];                                                     \
    wv_[2] = (pk)[(q4) + 2];                                                     \
    wv_[3] = (pk)[(q4) + 3];                                                     \
    pa = __builtin_bit_cast(bf16x8, wv_);                                        \
  }

  STAGE(0, ktbeg);

  int cur = 0;
  for (int kt = ktbeg; kt < ktend; ++kt) {
    if (kt + 1 < ktend) {
      STAGE(cur ^ 1, kt + 1);
      asm volatile("s_waitcnt vmcnt(4)" ::: "memory");
    } else {
      asm volatile("s_waitcnt vmcnt(0)" ::: "memory");
    }
    __builtin_amdgcn_s_barrier();
    __builtin_amdgcn_sched_barrier(0);

    const bool active = (kt <= ktlast);
    if (active) {
      const bool full = (kt < ktlast);
      const u16* ks = Ks[cur];
      const u16* vs = Vs[cur];

      f32x16 t00 = {}, t10 = {}, t01 = {}, t11 = {};
      __builtin_amdgcn_s_setprio(1);
#pragma unroll
      for (int cc = 0; cc < 4; ++cc) {
        const int ci = 2 * cc + lh;
        const bf16x8 kf0 = *(const bf16x8*)&ks[l31 * 64 + ((ci ^ (l31 & 7)) << 3)];
        const bf16x8 kf1 = *(const bf16x8*)&ks[(32 + l31) * 64 + ((ci ^ (l31 & 7)) << 3)];
        t00 = __builtin_amdgcn_mfma_f32_32x32x16_bf16(kf0, qf[0][cc], t00, 0, 0, 0);
        t01 = __builtin_amdgcn_mfma_f32_32x32x16_bf16(kf0, qf[1][cc], t01, 0, 0, 0);
        if (full) t10 = __builtin_amdgcn_mfma_f32_32x32x16_bf16(kf1, qf[0][cc], t10, 0, 0, 0);
        t11 = __builtin_amdgcn_mfma_f32_32x32x16_bf16(kf1, qf[1][cc], t11, 0, 0, 0);
      }
      __builtin_amdgcn_s_setprio(0);

      if (!full) {
#pragma unroll
        for (int r = 0; r < 16; ++r) {
          const int ko = (r & 3) + 8 * (r >> 2) + 4 * lh;
          if (ko > l31) { t00[r] = -3e38f; t11[r] = -3e38f; }
        }
      }

      u32 pk0[8], pk1[8];

#pragma unroll
      for (int r = 0; r < 16; ++r) t00[r] = exp2f(t00[r] - MFIX);
#pragma unroll
      for (int r = 0; r < 16; ++r) t01[r] = exp2f(t01[r] - MFIX);
      TREE16(l0, t00);
      TREE16(l1, t01);
#pragma unroll
      for (int j = 0; j < 8; ++j) {
        pk0[j] = packbf(t00[2 * j], t00[2 * j + 1]);
        pk1[j] = packbf(t01[2 * j], t01[2 * j + 1]);
      }
      __builtin_amdgcn_s_setprio(1);
#pragma unroll
      for (int kc = 0; kc < 2; ++kc) {
        const int q4 = kc * 4;
        MAKE_PA(pa0, pk0, q4)
        MAKE_PA(pa1, pk1, q4)
        const int ci = 2 * kc + lh;
        const bf16x8 vd0 = *(const bf16x8*)&vs[l31 * 64 + ((ci ^ (l31 & 7)) << 3)];
        const bf16x8 vd1 = *(const bf16x8*)&vs[(32 + l31) * 64 + ((ci ^ (l31 & 7)) << 3)];
        o00 = __builtin_amdgcn_mfma_f32_32x32x16_bf16(pa0, vd0, o00, 0, 0, 0);
        o01 = __builtin_amdgcn_mfma_f32_32x32x16_bf16(pa0, vd1, o01, 0, 0, 0);
        o10 = __builtin_amdgcn_mfma_f32_32x32x16_bf16(pa1, vd0, o10, 0, 0, 0);
        o11 = __builtin_amdgcn_mfma_f32_32x32x16_bf16(pa1, vd1, o11, 0, 0, 0);
      }
      __builtin_amdgcn_s_setprio(0);

      if (full) {
#pragma unroll
        for (int r = 0; r < 16; ++r) t10[r] = exp2f(t10[r] - MFIX);
        TREE16(l0, t10);
#pragma unroll
        for (int j = 0; j < 8; ++j) pk0[j] = packbf(t10[2 * j], t10[2 * j + 1]);
      }
#pragma unroll
      for (int r = 0; r < 16; ++r) t11[r] = exp2f(t11[r] - MFIX);
      TREE16(l1, t11);
#pragma unroll
      for (int j = 0; j < 8; ++j) pk1[j] = packbf(t11[2 * j], t11[2 * j + 1]);

      __builtin_amdgcn_s_setprio(1);
#pragma unroll
      for (int kc = 0; kc < 2; ++kc) {
        const int q4 = kc * 4;
        MAKE_PA(pa1, pk1, q4)
        const int ci = 2 * (kc + 2) + lh;
        const bf16x8 vd0 = *(const bf16x8*)&vs[l31 * 64 + ((ci ^ (l31 & 7)) << 3)];
        const bf16x8 vd1 = *(const bf16x8*)&vs[(32 + l31) * 64 + ((ci ^ (l31 & 7)) << 3)];
        if (full) {
          MAKE_PA(pa0, pk0, q4)
          o00 = __builtin_amdgcn_mfma_f32_32x32x16_bf16(pa0, vd0, o00, 0, 0, 0);
          o01 = __builtin_amdgcn_mfma_f32_32x32x16_bf16(pa0, vd1, o01, 0, 0, 0);
        }
        o10 = __builtin_amdgcn_mfma_f32_32x32x16_bf16(pa1, vd0, o10, 0, 0, 0);
        o11 = __builtin_amdgcn_mfma_f32_32x32x16_bf16(pa1, vd1, o11, 0, 0, 0);
      }
      __builtin_amdgcn_s_setprio(0);
    }

    asm volatile("s_waitcnt lgkmcnt(0)" ::: "memory");
    __builtin_amdgcn_s_barrier();
    cur ^= 1;
  }
#undef STAGE
#undef TREE16
#undef MAKE_PA

  const float l0t = l0 + __shfl_xor(l0, 32);
  const float l1t = l1 + __shfl_xor(l1, 32);
  u16* Oc = Opart + (size_t)c * 4096 * 1024;
#pragma unroll
  for (int r = 0; r < 16; ++r) {
    const int qo = (r & 3) + 8 * (r >> 2) + 4 * lh;
    u16* p0 = Oc + (size_t)(b * S + qbase + qo) * 1024 + h * 64 + l31;
    u16* p1 = p0 + (size_t)32 * 1024;
    p0[0] = f2bf(o00[r]);
    p0[32] = f2bf(o01[r]);
    p1[0] = f2bf(o10[r]);
    p1[32] = f2bf(o11[r]);
  }
  if (lh == 0) {
    Lpart[(size_t)c * 4096 * 16 + (size_t)(b * S + qbase + l31) * 16 + h] = l0t;
    Lpart[(size_t)c * 4096 * 16 + (size_t)(b * S + qbase + 32 + l31) * 16 + h] = l1t;
  }
}

// ---------------- combine partials: Obuf = (O0 + O1) / (l0 + l1) ----------------
__global__ __launch_bounds__(256) void combine(const u16* __restrict__ Opart,
                                               const float* __restrict__ Lpart,
                                               u16* __restrict__ Obuf) {
  const int i = blockIdx.x * 256 + threadIdx.x;
  const int row = i >> 7;
  const int cw = (i & 127) * 8;
  const int h = cw >> 6;
  const float l = Lpart[(size_t)row * 16 + h] + Lpart[(size_t)4096 * 16 + (size_t)row * 16 + h];
  const float inv = 1.0f / l;
  const bf16x8 a = *(const bf16x8*)(Opart + (size_t)row * 1024 + cw);
  const bf16x8 bq = *(const bf16x8*)(Opart + (size_t)4096 * 1024 + (size_t)row * 1024 + cw);
  u16 out[8];
#pragma unroll
  for (int j = 0; j < 8; ++j) out[j] = f2bf(((float)a[j] + (float)bq[j]) * inv);
  *(uint4*)(Obuf + (size_t)row * 1024 + cw) = *(uint4*)out;
}

extern "C" void kernel_launch(void* const* d_in, const int* in_sizes, int n_in,
                              void* d_out, int out_size, void* d_ws, size_t ws_size,
                              hipStream_t stream) {
  const float* x  = (const float*)d_in[0];
  const float* WQ = (const float*)d_in[1];
  const float* WK = (const float*)d_in[2];
  const float* WV = (const float*)d_in[3];
  const float* WO = (const float*)d_in[4];
  float* out = (float*)d_out;

  u16* xb    = (u16*)d_ws;                      // 4096*1024
  u16* WtQKV = xb + (size_t)4096 * 1024;        // 3072*1024
  u16* WtO   = WtQKV + (size_t)3072 * 1024;     // 1024*1024
  u16* QKV   = WtO + (size_t)1024 * 1024;       // 4096*3072
  u16* Obuf  = QKV + (size_t)4096 * 3072;       // 4096*1024
  u16* Vtg   = Obuf + (size_t)4096 * 1024;      // 2048*2048
  u16* Opart = Vtg + (size_t)2048 * 2048;       // 2 * 4096*1024 bf16
  float* Lpart = (float*)(Opart + (size_t)2 * 4096 * 1024);  // 2 * 4096*16 f32

  prep<<<dim3(32, 32, 5), 256, 0, stream>>>(x, xb, WQ, WK, WV, WO, WtQKV, WtO);

  gemm_bt<1, 1><<<dim3(32, 24), 256, 0, stream>>>(xb, WtQKV, QKV, Vtg, 4096, 3072, 1024);
  attn_kernel<<<dim3(16, 32), 256, 0, stream>>>(QKV, Vtg, Opart, Lpart);
  combine<<<2048, 256, 0, stream>>>(Opart, Lpart, Obuf);
  gemm_bt<0, 0><<<dim3(32, 8), 256, 0, stream>>>(Obuf, WtO, out, nullptr, 4096, 1024, 1024);
}